// Round 2
// baseline (474.848 us; speedup 1.0000x reference)
//
#include <hip/hip_runtime.h>

#define Bdim 32
#define Ndim 577
#define Cdim 768
#define Hdim 12
#define Ddim 64
#define Mdim (Bdim*Ndim)   // 18464
#define VSTRIDE 640        // padded token stride for v^T (kt=9 staging stays in-bounds)
#define TSTRIDE 152        // v-transpose LDS tile token stride (304B rows, 16B-aligned)
#define QSCALE 0.18033688f // 0.125 * log2(e): attn uses exp2, so fold log2e into q
#define MGRP 19            // ceil(145/8) m-strip groups for XCD swizzle

typedef __attribute__((ext_vector_type(4))) float f32x4;
typedef __attribute__((ext_vector_type(8))) __bf16 bf16x8;
typedef __attribute__((ext_vector_type(4))) __bf16 bf16x4;

__device__ __forceinline__ void gl_lds16(const __bf16* g, __bf16* l) {
  __builtin_amdgcn_global_load_lds((const __attribute__((address_space(1))) void*)g,
                                   (__attribute__((address_space(3))) void*)l, 16, 0, 0);
}

// ---------------- fp32 -> bf16 convert (vectorized) --------------------------
__global__ __launch_bounds__(256) void f32_to_bf16(const float4* __restrict__ in,
                                                   bf16x4* __restrict__ out, int n4) {
  int i = blockIdx.x * 256 + threadIdx.x;
  if (i < n4) {
    float4 v = in[i];
    bf16x4 o = {(__bf16)v.x, (__bf16)v.y, (__bf16)v.z, (__bf16)v.w};
    out[i] = o;
  }
}

// ------------- transpose + downcast: in fp32 [R][Cc] -> out bf16 [Cc][R] -----
__global__ __launch_bounds__(256) void transpose_f32_bf16(const float* __restrict__ in,
                                                          __bf16* __restrict__ out,
                                                          int R, int Cc) {
  __shared__ float tile[64][65];
  int bx = blockIdx.x * 64;           // col base (Cc dim)
  int by = blockIdx.y * 64;           // row base (R dim)
  int tx = threadIdx.x & 63, ty = threadIdx.x >> 6;
  for (int i = ty; i < 64; i += 4) {
    int r = by + i, c = bx + tx;
    tile[i][tx] = (r < R && c < Cc) ? in[(size_t)r * Cc + c] : 0.f;
  }
  __syncthreads();
  for (int i = ty; i < 64; i += 4) {
    int r = bx + i, c = by + tx;      // out is [Cc][R]
    if (r < Cc && c < R) out[(size_t)r * R + c] = (__bf16)tile[tx][i];
  }
}

// -------- shared GEMM-BT mainloop: C[128x128] tile, K=768, BK=64 -------------
// Round-1 changes vs the proven 445.9us core (sync structure stays
// compiler-managed -- no inline waitcnt):
//  (a) double-buffered LDS + 1-tile-ahead prefetch: stage(t+1) issues BEFORE
//      compute(t); the single __syncthreads() per K-tile drains it (compiler
//      emits vmcnt(0) lgkmcnt(0) before s_barrier). One barrier/tile vs two.
//  (b) T2 XOR swizzle in the contraction dim: LDS chunk c of row r holds
//      global chunk c ^ (r&3) ^ ((r>>2)&3); applied on the per-lane GLOBAL
//      source at staging (LDS dest stays linear: global_load_lds rule), and
//      on the ds_read_b128 chunk select. Each 8-lane batch then covers all
//      32 banks exactly once (was 8-way conflicted at 64B row stride).
__device__ __forceinline__ void stage_tile(const __bf16* __restrict__ A,
                                           const __bf16* __restrict__ BT,
                                           int m0, int n0, int k0,
                                           __bf16* As, __bf16* Bs) {
  const int t = threadIdx.x;
  const int lane = t & 63, w = t >> 6;
  const int cs = (lane & 3) ^ ((lane >> 2) & 3) ^ ((lane >> 4) & 3);
  #pragma unroll
  for (int e = 0; e < 4; ++e) {
    int h = e >> 1;
    int j = ((e & 1) << 2) | w;                 // row-group 0..7
    int row = j * 16 + (lane >> 2);             // 0..127
    int col = k0 + h * 32 + cs * 8;             // pre-swizzled source chunk
    int ar = m0 + row; if (ar > Mdim - 1) ar = Mdim - 1;   // M tail clamp
    gl_lds16(A  + (size_t)ar * 768 + col, As + h * 4096 + j * 512 + lane * 8);
    gl_lds16(BT + (size_t)(n0 + row) * 768 + col, Bs + h * 4096 + j * 512 + lane * 8);
  }
}

__device__ __forceinline__ void gemm_bt_core(const __bf16* __restrict__ A,
                                             const __bf16* __restrict__ BT,
                                             int m0, int n0,
                                             __bf16* As, __bf16* Bs,
                                             f32x4 acc[4][4]) {
  const int t = threadIdx.x;
  const int lane = t & 63, w = t >> 6;
  const int quad = lane >> 4, l16 = lane & 15;
  const int wm = w >> 1, wn = w & 1;
  const int ksw = (quad ^ (l16 & 3) ^ ((l16 >> 2) & 3)) << 3;  // swizzled read chunk (elems)

  stage_tile(A, BT, m0, n0, 0, As, Bs);
  __syncthreads();
  for (int k0 = 0; k0 < 768; k0 += 64) {
    const int buf = (k0 >> 6) & 1;
    if (k0 < 704)
      stage_tile(A, BT, m0, n0, k0 + 64, As + (buf ^ 1) * 8192, Bs + (buf ^ 1) * 8192);
    #pragma unroll
    for (int s = 0; s < 2; ++s) {
      bf16x8 a[4], b[4];
      #pragma unroll
      for (int i = 0; i < 4; ++i) {
        a[i] = *(const bf16x8*)(As + buf * 8192 + s * 4096 + (wm * 64 + i * 16 + l16) * 32 + ksw);
        b[i] = *(const bf16x8*)(Bs + buf * 8192 + s * 4096 + (wn * 64 + i * 16 + l16) * 32 + ksw);
      }
      #pragma unroll
      for (int mt = 0; mt < 4; ++mt)
        #pragma unroll
        for (int nt = 0; nt < 4; ++nt)
          acc[mt][nt] = __builtin_amdgcn_mfma_f32_16x16x32_bf16(a[mt], b[nt], acc[mt][nt], 0, 0, 0);
    }
    __syncthreads();   // drains prefetch (vmcnt0) + fragment reads; 1 barrier/tile
  }
}

// XCD swizzle decode: all nb n-blocks of one m-strip land on one XCD
// (strip % 8 == linear % 8 under round-robin dispatch). Returns false for pads.
__device__ __forceinline__ bool xcd_decode(int lin, int nb, int mb, int& n, int& m) {
  int x8 = lin & 7;
  int rest = lin >> 3;
  n = rest % nb;
  int mg = rest / nb;
  m = mg * 8 + x8;
  return m < mb;
}

// ---------------- kernel 1a: Q/K GEMM + bias + RoPE (cols 0..1535) -----------
__global__ __launch_bounds__(256) void qk_kernel(const __bf16* __restrict__ x,
                                                 const __bf16* __restrict__ wqkvT,
                                                 const float* __restrict__ b_qkv,
                                                 const float* __restrict__ rs,
                                                 const float* __restrict__ rc,
                                                 __bf16* __restrict__ q,
                                                 __bf16* __restrict__ k) {
  __shared__ __bf16 As[2 * 2 * 128 * 32];
  __shared__ __bf16 Bs[2 * 2 * 128 * 32];
  int nb, mbk;
  if (!xcd_decode(blockIdx.x, 12, 145, nb, mbk)) return;
  const int n0 = nb * 128, m0 = mbk * 128;

  f32x4 acc[4][4];
  const f32x4 fz = {0.f, 0.f, 0.f, 0.f};
  for (int i = 0; i < 4; ++i) for (int j = 0; j < 4; ++j) acc[i][j] = fz;
  gemm_bt_core(x, wqkvT, m0, n0, As, Bs, acc);

  const int lane = threadIdx.x & 63, w = threadIdx.x >> 6;
  const int quad = lane >> 4, l16 = lane & 15;
  const int wm = w >> 1, wn = w & 1;
  const int colbase = n0 + wn * 64;          // 64-aligned -> one (matrix, head)
  const int matrix = colbase / 768;          // 0=q 1=k
  const int head = (colbase % 768) / 64;

  #pragma unroll
  for (int mt = 0; mt < 4; ++mt) {
    int mbase = m0 + wm * 64 + mt * 16 + quad * 4;
    #pragma unroll
    for (int r = 0; r < 4; ++r) {
      int m = mbase + r;
      if (m >= Mdim) continue;
      int bb = m / 577, tok = m % 577;
      #pragma unroll
      for (int nt = 0; nt < 4; ++nt) {
        int d = nt * 16 + l16;
        float val = acc[mt][nt][r] + b_qkv[colbase + d];
        if (tok > 0) {
          float partner = acc[mt][nt ^ 2][r] + b_qkv[colbase + (d ^ 32)];
          float sn = rs[(size_t)(tok - 1) * 64 + d];
          float cs = rc[(size_t)(tok - 1) * 64 + d];
          float rot = (d < 32) ? -partner : partner;
          val = val * cs + rot * sn;
        }
        __bf16* dst;
        if (matrix == 0) { val *= QSCALE; dst = q; } else dst = k;
        dst[((size_t)(bb * 12 + head) * 577 + tok) * 64 + d] = (__bf16)val;
      }
    }
  }
}

// ---------------- kernel 1b: V GEMM + bias + LDS-transpose (cols 1536..2303) -
__global__ __launch_bounds__(256) void v_kernel(const __bf16* __restrict__ x,
                                                const __bf16* __restrict__ wqkvT,
                                                const float* __restrict__ b_qkv,
                                                __bf16* __restrict__ vt) {
  __shared__ __bf16 As[2 * 2 * 128 * 32];
  __shared__ __bf16 Bs[2 * 2 * 128 * 32];
  __bf16* Ts = As;   // v-transpose half-tile aliases As (free after core's last barrier)
  int nb, mbk;
  if (!xcd_decode(blockIdx.x, 6, 145, nb, mbk)) return;
  const int n0 = 1536 + nb * 128, m0 = mbk * 128;

  f32x4 acc[4][4];
  const f32x4 fz = {0.f, 0.f, 0.f, 0.f};
  for (int i = 0; i < 4; ++i) for (int j = 0; j < 4; ++j) acc[i][j] = fz;
  gemm_bt_core(x, wqkvT, m0, n0, As, Bs, acc);

  const int t = threadIdx.x;
  const int lane = t & 63, w = t >> 6;
  const int quad = lane >> 4, l16 = lane & 15;
  const int wm = w >> 1, wn = w & 1;
  const int colbase = n0 + wn * 64;

  #pragma unroll
  for (int h = 0; h < 2; ++h) {
    __syncthreads();
    if (wn == h) {
      #pragma unroll
      for (int mt = 0; mt < 4; ++mt) {
        int tokbase = wm * 64 + mt * 16 + quad * 4;
        #pragma unroll
        for (int r = 0; r < 4; ++r) {
          #pragma unroll
          for (int nt = 0; nt < 4; ++nt) {
            int dl = nt * 16 + l16;
            Ts[dl * TSTRIDE + tokbase + r] =
                (__bf16)(acc[mt][nt][r] + b_qkv[colbase + dl]);
          }
        }
      }
    }
    __syncthreads();
    int hh = (n0 + h * 64 - 1536) / 64;    // head for this half
    #pragma unroll
    for (int it = 0; it < 4; ++it) {
      int c = it * 256 + t;
      int dl = c >> 4, chunk = c & 15;
      bf16x8 vv = *(const bf16x8*)(Ts + dl * TSTRIDE + chunk * 8);
      #pragma unroll
      for (int j = 0; j < 8; ++j) {
        int m = m0 + chunk * 8 + j;
        if (m < Mdim) {
          int bb = m / 577, tok = m % 577;
          vt[((size_t)(bb * 12 + hh) * 64 + dl) * VSTRIDE + tok] = vv[j];
        }
      }
    }
  }
}

// ---------------- kernel 2: flash attention (softmax-lite) -------------------
__global__ __launch_bounds__(256) void attn_kernel(const __bf16* __restrict__ q,
                                                   const __bf16* __restrict__ k,
                                                   const __bf16* __restrict__ vt,
                                                   __bf16* __restrict__ ao) {
  __shared__ __bf16 qs[4096];
  __shared__ __bf16 ks[4096];
  __shared__ __bf16 vs[4096];
  __shared__ __bf16 ps[64 * 72];   // P strip, padded stride 72 (16B-aligned rows)

  // XCD swizzle: all 10 q-tiles of one (b,h) on one XCD -> K/V L2-resident
  const int x8 = blockIdx.x & 7;
  const int rest = blockIdx.x >> 3;
  const int qt = rest % 10;
  const int bh = (rest / 10) * 8 + x8;

  const int t = threadIdx.x;
  const int lane = t & 63, w = t >> 6;
  const int quad = lane >> 4, l16 = lane & 15;

  const __bf16* qbase = q + (size_t)bh * 577 * 64;
  const __bf16* kbase = k + (size_t)bh * 577 * 64;
  const __bf16* vbase = vt + (size_t)bh * 64 * VSTRIDE;

  // stage q tile once: 512 groups of 16B (rows >=577 read poison, discarded)
  #pragma unroll
  for (int p = 0; p < 2; ++p) {
    int g = p * 256 + t;
    int d8 = g >> 6, tok = g & 63;
    gl_lds16(qbase + (size_t)(qt * 64 + tok) * 64 + d8 * 8, qs + (size_t)g * 8);
  }

  f32x4 O[4]; const f32x4 fz = {0.f, 0.f, 0.f, 0.f};
  for (int i = 0; i < 4; ++i) O[i] = fz;
  float l_part[4] = {0.f, 0.f, 0.f, 0.f};

  for (int kt = 0; kt < 10; ++kt) {
    __syncthreads();   // previous tile's consumers done before restaging
    #pragma unroll
    for (int p = 0; p < 2; ++p) {
      int g = p * 256 + t;
      int d8 = g >> 6, tok = g & 63;
      gl_lds16(kbase + (size_t)(kt * 64 + tok) * 64 + d8 * 8, ks + (size_t)g * 8);
      gl_lds16(vbase + (size_t)(g & 63) * VSTRIDE + kt * 64 + (g >> 6) * 8, vs + (size_t)g * 8);
    }
    __syncthreads();   // staging drained (vmcnt(0) before barrier)

    // S = q k^T  (q pre-scaled by 0.125*log2e)
    f32x4 S[4]; for (int i = 0; i < 4; ++i) S[i] = fz;
    #pragma unroll
    for (int step = 0; step < 2; ++step) {
      bf16x8 a = *(const bf16x8*)(qs + (size_t)((step * 4 + quad) * 64 + w * 16 + l16) * 8);
      #pragma unroll
      for (int nt = 0; nt < 4; ++nt) {
        bf16x8 b = *(const bf16x8*)(ks + (size_t)((step * 4 + quad) * 64 + nt * 16 + l16) * 8);
        S[nt] = __builtin_amdgcn_mfma_f32_16x16x32_bf16(a, b, S[nt], 0, 0, 0);
      }
    }

    // mask invalid keys (only kt==9: 577 = 9*64 + 1); exp2(-1e30) -> 0
    int kv_left = 577 - kt * 64;
    if (kv_left < 64) {
      #pragma unroll
      for (int nt = 0; nt < 4; ++nt) {
        int c = nt * 16 + l16;
        if (c >= kv_left) { S[nt][0] = -1e30f; S[nt][1] = -1e30f; S[nt][2] = -1e30f; S[nt][3] = -1e30f; }
      }
    }

    // softmax-lite: exp2, per-lane l accumulation, P -> LDS (A-layout via ps)
    #pragma unroll
    for (int r = 0; r < 4; ++r) {
      #pragma unroll
      for (int nt = 0; nt < 4; ++nt) {
        float e = exp2f(S[nt][r]);
        l_part[r] += e;
        ps[(size_t)(w * 16 + quad * 4 + r) * 72 + nt * 16 + l16] = (__bf16)e;
      }
    }

    // O += P @ V   (P strip is wave-private; in-wave DS ordering covers w->r)
    #pragma unroll
    for (int step = 0; step < 2; ++step) {
      bf16x8 a = *(const bf16x8*)(ps + (size_t)(w * 16 + l16) * 72 + step * 32 + quad * 8);
      #pragma unroll
      for (int dt = 0; dt < 4; ++dt) {
        bf16x8 b = *(const bf16x8*)(vs + (size_t)((step * 4 + quad) * 64 + dt * 16 + l16) * 8);
        O[dt] = __builtin_amdgcn_mfma_f32_16x16x32_bf16(a, b, O[dt], 0, 0, 0);
      }
    }
  }

  // epilogue: reduce l across the 16 col-lanes, normalize, write ao[B*N, C]
  const int bb = bh / 12, hh = bh % 12;
  const int qrow0 = qt * 64 + w * 16 + quad * 4;
  #pragma unroll
  for (int r = 0; r < 4; ++r) {
    float l = l_part[r];
    l += __shfl_xor(l, 1); l += __shfl_xor(l, 2);
    l += __shfl_xor(l, 4); l += __shfl_xor(l, 8);
    int row = qrow0 + r;
    if (row < 577) {
      float inv = 1.f / l;
      size_t base = ((size_t)(bb * 577 + row)) * 768 + hh * 64;
      #pragma unroll
      for (int dt = 0; dt < 4; ++dt)
        ao[base + dt * 16 + l16] = (__bf16)(O[dt][r] * inv);
    }
  }
}

// ---------------- kernel 3: proj GEMM + bias -> fp32 out ---------------------
__global__ __launch_bounds__(256) void proj_kernel(const __bf16* __restrict__ ao,
                                                   const __bf16* __restrict__ wprojT,
                                                   const float* __restrict__ b_proj,
                                                   float* __restrict__ out) {
  __shared__ __bf16 As[2 * 2 * 128 * 32];
  __shared__ __bf16 Bs[2 * 2 * 128 * 32];
  int nb, mbk;
  if (!xcd_decode(blockIdx.x, 6, 145, nb, mbk)) return;
  const int n0 = nb * 128, m0 = mbk * 128;

  f32x4 acc[4][4];
  const f32x4 fz = {0.f, 0.f, 0.f, 0.f};
  for (int i = 0; i < 4; ++i) for (int j = 0; j < 4; ++j) acc[i][j] = fz;
  gemm_bt_core(ao, wprojT, m0, n0, As, Bs, acc);

  const int lane = threadIdx.x & 63, w = threadIdx.x >> 6;
  const int quad = lane >> 4, l16 = lane & 15;
  const int wm = w >> 1, wn = w & 1;
  const int colbase = n0 + wn * 64;

  #pragma unroll
  for (int mt = 0; mt < 4; ++mt) {
    int mbase = m0 + wm * 64 + mt * 16 + quad * 4;
    #pragma unroll
    for (int r = 0; r < 4; ++r) {
      int m = mbase + r;
      if (m >= Mdim) continue;
      #pragma unroll
      for (int nt = 0; nt < 4; ++nt) {
        int c = colbase + nt * 16 + l16;
        out[(size_t)m * 768 + c] = acc[mt][nt][r] + b_proj[c];
      }
    }
  }
}

// ---------------- launch -----------------------------------------------------
extern "C" void kernel_launch(void* const* d_in, const int* in_sizes, int n_in,
                              void* d_out, int out_size, void* d_ws, size_t ws_size,
                              hipStream_t stream) {
  const float* x      = (const float*)d_in[0];
  const float* w_qkv  = (const float*)d_in[1];
  const float* b_qkv  = (const float*)d_in[2];
  const float* w_proj = (const float*)d_in[3];
  const float* b_proj = (const float*)d_in[4];
  const float* rsn    = (const float*)d_in[5];
  const float* rcs    = (const float*)d_in[6];
  float* out = (float*)d_out;

  // workspace layout (bf16 elements); ao aliases x_bf (x consumed before attn)
  constexpr size_t QK_E = (size_t)Bdim * Hdim * Ndim * Ddim;      // 14,180,352
  constexpr size_t VT_E = (size_t)Bdim * Hdim * Ddim * VSTRIDE;   // 15,728,640
  constexpr size_t AO_E = (size_t)Mdim * Cdim;                    // 14,180,352
  __bf16* q      = (__bf16*)d_ws;
  __bf16* k      = q + QK_E;
  __bf16* vt     = k + QK_E;
  __bf16* ao     = vt + VT_E;        // also holds x_bf before attn runs
  __bf16* xb     = ao;
  __bf16* wqkvT  = ao + AO_E;
  __bf16* wprojT = wqkvT + (size_t)2304 * 768;
  // total: ~121 MB

  f32_to_bf16<<<13848, 256, 0, stream>>>((const float4*)x, (bf16x4*)xb,
                                         (int)(AO_E / 4));
  transpose_f32_bf16<<<dim3(36, 12), 256, 0, stream>>>(w_qkv, wqkvT, 768, 2304);
  transpose_f32_bf16<<<dim3(12, 12), 256, 0, stream>>>(w_proj, wprojT, 768, 768);
  qk_kernel<<<8 * MGRP * 12, 256, 0, stream>>>(xb, wqkvT, b_qkv, rsn, rcs, q, k);
  v_kernel<<<8 * MGRP * 6, 256, 0, stream>>>(xb, wqkvT, b_qkv, vt);
  attn_kernel<<<3840, 256, 0, stream>>>(q, k, vt, ao);
  proj_kernel<<<8 * MGRP * 6, 256, 0, stream>>>(ao, wprojT, b_proj, out);
}

// Round 3
// 462.018 us; speedup vs baseline: 1.0278x; 1.0278x over previous
//
#include <hip/hip_runtime.h>

#define Bdim 32
#define Ndim 577
#define Cdim 768
#define Hdim 12
#define Ddim 64
#define Mdim (Bdim*Ndim)   // 18464
#define VSTRIDE 640        // padded token stride for v^T (kt=9 staging stays in-bounds)
#define QSCALE 0.18033688f // 0.125 * log2(e): attn uses exp2, so fold log2e into q
#define NT 12              // K = 768 = 12 K-tiles of BK=64

typedef __attribute__((ext_vector_type(4))) float f32x4;
typedef __attribute__((ext_vector_type(8))) __bf16 bf16x8;
typedef __attribute__((ext_vector_type(4))) __bf16 bf16x4;

__device__ __forceinline__ void gl_lds16(const __bf16* g, __bf16* l) {
  __builtin_amdgcn_global_load_lds((const __attribute__((address_space(1))) void*)g,
                                   (__attribute__((address_space(3))) void*)l, 16, 0, 0);
}

// ---------------- fp32 -> bf16 convert (vectorized) --------------------------
__global__ __launch_bounds__(256) void f32_to_bf16(const float4* __restrict__ in,
                                                   bf16x4* __restrict__ out, int n4) {
  int i = blockIdx.x * 256 + threadIdx.x;
  if (i < n4) {
    float4 v = in[i];
    bf16x4 o = {(__bf16)v.x, (__bf16)v.y, (__bf16)v.z, (__bf16)v.w};
    out[i] = o;
  }
}

// ------------- transpose + downcast: in fp32 [R][Cc] -> out bf16 [Cc][R] -----
// permqk!=0: for out rows < 1536 (q/k weight cols), permute within each head's
// 64 cols: physical p holds logical d(p) = (p&15)|((p&16)<<1)|((p&32)>>1).
// This puts RoPE partners (d, d^32) at physical (p, p^16) -> same lane, nf^1.
__global__ __launch_bounds__(256) void transpose_f32_bf16(const float* __restrict__ in,
                                                          __bf16* __restrict__ out,
                                                          int R, int Cc, int permqk) {
  __shared__ float tile[64][65];
  int bx = blockIdx.x * 64;           // col base (Cc dim)
  int by = blockIdx.y * 64;           // row base (R dim)
  int tx = threadIdx.x & 63, ty = threadIdx.x >> 6;
  for (int i = ty; i < 64; i += 4) {
    int r = by + i, c = bx + tx;
    int cl = c;
    if (permqk && c < 1536) {
      int p = c & 63;
      cl = (c & ~63) | ((p & 15) | ((p & 16) << 1) | ((p & 32) >> 1));
    }
    tile[i][tx] = (r < R && c < Cc) ? in[(size_t)r * Cc + cl] : 0.f;
  }
  __syncthreads();
  for (int i = ty; i < 64; i += 4) {
    int r = bx + i, c = by + tx;      // out is [Cc][R]
    if (r < Cc && c < R) out[(size_t)r * R + c] = (__bf16)tile[tx][i];
  }
}

// ============ 256x256 4-phase/K-tile GEMM core (T2+T3+T4+T5) =================
// LDS: per matrix 2 K-tile buffers x 2 halves x [128 rows][64 k] bf16 (swizzled).
// Swizzle: 16B chunk c of row r stores global chunk c^(r&7)  (inverse applied
// on the per-lane GLOBAL source at staging; LDS dest stays linear: rule #21).
// 8 waves (2M x 4N); wave output 128x64, interleaved so quadrant qi/qj of every
// wave lies in A-half qi / B-half qj. Phase order (qi,qj): (0,0),(0,1),(1,1),(1,0)
// frees A0 after ph1, B1 after ph2, A1+B0 after ph3. Staging per phase:
//   ph0: A1(t+1)  ph1: B0(t+1)  ph2: A0(t+2)  ph3: B1(t+2)
// -> each stage overwrites a half freed >=2 barriers earlier.
// vmcnt(4) at ph3 (once per K-tile, counted: completes all of tile t+1, leaves
// the ph2/ph3 t+2 halves in flight); vmcnt(0) only at t==NT-2.

#define HSLOT(b,h) (((b)*2+(h))*8192)

__device__ __forceinline__ void stageA(const __bf16* __restrict__ A, int m0,
                                       int k0, int h, __bf16* lds, int tid) {
  #pragma unroll
  for (int i = 0; i < 2; ++i) {
    int idx = i * 512 + tid;          // half = 128 rows x 8 chunks = 1024 chunks
    int rl = idx >> 3, c = idx & 7;
    int row = m0 + h * 128 + rl;
    if (row > Mdim - 1) row = Mdim - 1;          // M tail clamp
    gl_lds16(A + (size_t)row * 768 + k0 + ((c ^ (rl & 7)) << 3), lds + (idx << 3));
  }
}

__device__ __forceinline__ void stageB(const __bf16* __restrict__ BT, int n0,
                                       int k0, int h, __bf16* lds, int tid) {
  #pragma unroll
  for (int i = 0; i < 2; ++i) {
    int idx = i * 512 + tid;
    int rl = idx >> 3, c = idx & 7;
    int row = n0 + h * 128 + rl;                 // always in-bounds for our N
    gl_lds16(BT + (size_t)row * 768 + k0 + ((c ^ (rl & 7)) << 3), lds + (idx << 3));
  }
}

__device__ __forceinline__ void gemm256_core(const __bf16* __restrict__ A,
                                             const __bf16* __restrict__ BT,
                                             int m0, int n0,
                                             __bf16* __restrict__ smA,
                                             __bf16* __restrict__ smB,
                                             f32x4 (&acc)[2][4][2][2]) {
  const int tid = threadIdx.x;
  const int lane = tid & 63, w = tid >> 6;
  const int quad = lane >> 4, l16 = lane & 15;
  const int wm = w >> 2, wn = w & 3;

  // prologue: tile0 fully + A0(1), B1(1); vmcnt(4) leaves exactly those 4 loads
  stageA(A, m0, 0, 0, smA + HSLOT(0, 0), tid);
  stageA(A, m0, 0, 1, smA + HSLOT(0, 1), tid);
  stageB(BT, n0, 0, 0, smB + HSLOT(0, 0), tid);
  stageB(BT, n0, 0, 1, smB + HSLOT(0, 1), tid);
  stageA(A, m0, 64, 0, smA + HSLOT(1, 0), tid);
  stageB(BT, n0, 64, 1, smB + HSLOT(1, 1), tid);
  asm volatile("s_waitcnt vmcnt(4)" ::: "memory");
  __builtin_amdgcn_s_barrier();

  const int arow = wm * 64 + l16;                 // + mf*16
  const int brow = wn * 32 + l16;                 // + nf*16
  const int kx = ((quad ^ (l16 & 7)) << 3);       // ks=0 swizzled chunk offset (elems)
                                                  // ks=1 is kx ^ 32 (chunk bit2)

  #pragma unroll 2
  for (int t = 0; t < NT; ++t) {
    const int buf = t & 1;
    #pragma unroll
    for (int ph = 0; ph < 4; ++ph) {
      const int qi = ph >> 1;
      const int qj = (ph == 1 || ph == 2) ? 1 : 0;
      const __bf16* Ab = smA + HSLOT(buf, qi);
      const __bf16* Bb = smB + HSLOT(buf, qj);
      bf16x8 a[4][2], b[2][2];
      #pragma unroll
      for (int mf = 0; mf < 4; ++mf) {
        a[mf][0] = *(const bf16x8*)(Ab + (arow + mf * 16) * 64 + kx);
        a[mf][1] = *(const bf16x8*)(Ab + (arow + mf * 16) * 64 + (kx ^ 32));
      }
      #pragma unroll
      for (int nf = 0; nf < 2; ++nf) {
        b[nf][0] = *(const bf16x8*)(Bb + (brow + nf * 16) * 64 + kx);
        b[nf][1] = *(const bf16x8*)(Bb + (brow + nf * 16) * 64 + (kx ^ 32));
      }
      if (ph == 0) { if (t + 1 < NT) stageA(A, m0, (t + 1) << 6, 1, smA + HSLOT((t + 1) & 1, 1), tid); }
      if (ph == 1) { if (t + 1 < NT) stageB(BT, n0, (t + 1) << 6, 0, smB + HSLOT((t + 1) & 1, 0), tid); }
      if (ph == 2) { if (t + 2 < NT) stageA(A, m0, (t + 2) << 6, 0, smA + HSLOT(buf, 0), tid); }
      if (ph == 3) {
        if (t + 2 < NT) stageB(BT, n0, (t + 2) << 6, 1, smB + HSLOT(buf, 1), tid);
        if (t < NT - 2)       { asm volatile("s_waitcnt vmcnt(4)" ::: "memory"); }
        else if (t == NT - 2) { asm volatile("s_waitcnt vmcnt(0)" ::: "memory"); }
        __builtin_amdgcn_sched_barrier(0);
      }
      __builtin_amdgcn_s_barrier();
      asm volatile("s_waitcnt lgkmcnt(0)" ::: "memory");
      __builtin_amdgcn_sched_barrier(0);
      __builtin_amdgcn_s_setprio(1);
      #pragma unroll
      for (int ks = 0; ks < 2; ++ks)
        #pragma unroll
        for (int mf = 0; mf < 4; ++mf)
          #pragma unroll
          for (int nf = 0; nf < 2; ++nf)
            acc[qi][mf][qj][nf] = __builtin_amdgcn_mfma_f32_16x16x32_bf16(
                a[mf][ks], b[nf][ks], acc[qi][mf][qj][nf], 0, 0, 0);
      __builtin_amdgcn_s_setprio(0);
      __builtin_amdgcn_s_barrier();
    }
  }
}

// frag (qi,mf,qj,nf) reg r maps to: row = m0+qi*128+wm*64+mf*16+quad*4+r
//                                   col = n0+qj*128+wn*32+nf*16+l16

// ---------------- kernel 1a: Q/K GEMM + bias + RoPE (cols 0..1535) -----------
__global__ __launch_bounds__(512, 2) void qk_kernel(const __bf16* __restrict__ x,
                                                    const __bf16* __restrict__ wqkvT,
                                                    const float* __restrict__ b_qkv,
                                                    const float* __restrict__ rs,
                                                    const float* __restrict__ rc,
                                                    __bf16* __restrict__ q,
                                                    __bf16* __restrict__ k) {
  __shared__ __bf16 sm[65536];       // 128 KB: smA | smB
  const int nb = blockIdx.x % 6, mb = blockIdx.x / 6;
  const int n0 = nb * 256, m0 = mb * 256;

  f32x4 acc[2][4][2][2];
  const f32x4 fz = {0.f, 0.f, 0.f, 0.f};
  #pragma unroll
  for (int i = 0; i < 2; ++i)
    #pragma unroll
    for (int j = 0; j < 4; ++j)
      #pragma unroll
      for (int u = 0; u < 2; ++u)
        #pragma unroll
        for (int v = 0; v < 2; ++v) acc[i][j][u][v] = fz;

  gemm256_core(x, wqkvT, m0, n0, sm, sm + 32768, acc);

  const int lane = threadIdx.x & 63, w = threadIdx.x >> 6;
  const int quad = lane >> 4, l16 = lane & 15;
  const int wm = w >> 2, wn = w & 3;

  #pragma unroll
  for (int qi = 0; qi < 2; ++qi)
    #pragma unroll
    for (int mf = 0; mf < 4; ++mf) {
      int mbase = m0 + qi * 128 + wm * 64 + mf * 16 + quad * 4;
      #pragma unroll
      for (int qj = 0; qj < 2; ++qj)
        #pragma unroll
        for (int nf = 0; nf < 2; ++nf) {
          int col = n0 + qj * 128 + wn * 32 + nf * 16 + l16;   // physical col
          int matrix = col / 768;                               // 0=q 1=k
          int within = col % 768;
          int head = within / 64, p = within % 64;
          int d = (p & 15) | ((p & 16) << 1) | ((p & 32) >> 1); // logical d
          float bias   = b_qkv[matrix * 768 + head * 64 + d];
          float bias_p = b_qkv[matrix * 768 + head * 64 + (d ^ 32)];
          #pragma unroll
          for (int r = 0; r < 4; ++r) {
            int m = mbase + r;
            if (m >= Mdim) continue;
            int bb = m / 577, tok = m % 577;
            float val = acc[qi][mf][qj][nf][r] + bias;
            if (tok > 0) {
              float partner = acc[qi][mf][qj][nf ^ 1][r] + bias_p; // physical p^16 = logical d^32
              float sn = rs[(size_t)(tok - 1) * 64 + d];
              float cs = rc[(size_t)(tok - 1) * 64 + d];
              float rot = (p & 16) ? partner : -partner;           // d<32 <-> (p&16)==0
              val = val * cs + rot * sn;
            }
            __bf16* dst;
            if (matrix == 0) { val *= QSCALE; dst = q; } else dst = k;
            dst[((size_t)(bb * 12 + head) * 577 + tok) * 64 + d] = (__bf16)val;
          }
        }
    }
}

// ---------------- kernel 1b: V GEMM + bias + LDS-transpose (cols 1536..2303) -
__global__ __launch_bounds__(512, 2) void v_kernel(const __bf16* __restrict__ x,
                                                   const __bf16* __restrict__ wqkvT,
                                                   const float* __restrict__ b_qkv,
                                                   __bf16* __restrict__ vt) {
  __shared__ __bf16 sm[65536];       // GEMM: smA|smB; epilogue: Ts[256 col][256 tok]
  const int nb = blockIdx.x % 3, mb = blockIdx.x / 3;
  const int n0loc = nb * 256;                 // col within v section [0,768)
  const int n0abs = 1536 + n0loc;             // row in wqkvT
  const int m0 = mb * 256;

  f32x4 acc[2][4][2][2];
  const f32x4 fz = {0.f, 0.f, 0.f, 0.f};
  #pragma unroll
  for (int i = 0; i < 2; ++i)
    #pragma unroll
    for (int j = 0; j < 4; ++j)
      #pragma unroll
      for (int u = 0; u < 2; ++u)
        #pragma unroll
        for (int v = 0; v < 2; ++v) acc[i][j][u][v] = fz;

  gemm256_core(x, wqkvT, m0, n0abs, sm, sm + 32768, acc);

  const int tid = threadIdx.x;
  const int lane = tid & 63, w = tid >> 6;
  const int quad = lane >> 4, l16 = lane & 15;
  const int wm = w >> 2, wn = w & 3;
  char* smc = (char*)sm;

  // write transposed tile: Ts byte = cl*512 + tok*2, XOR-swizzled ((cl&7)<<4).
  // (core's final barrier already drained all LDS reads -> safe to overwrite)
  #pragma unroll
  for (int qi = 0; qi < 2; ++qi)
    #pragma unroll
    for (int mf = 0; mf < 4; ++mf) {
      int tk = qi * 128 + wm * 64 + mf * 16 + quad * 4;   // token-local (mult of 4)
      #pragma unroll
      for (int qj = 0; qj < 2; ++qj)
        #pragma unroll
        for (int nf = 0; nf < 2; ++nf) {
          int cl = qj * 128 + wn * 32 + nf * 16 + l16;    // col-local 0..255
          float bias = b_qkv[1536 + n0loc + cl];
          f32x4 av = acc[qi][mf][qj][nf];
          bf16x4 pk = {(__bf16)(av[0] + bias), (__bf16)(av[1] + bias),
                       (__bf16)(av[2] + bias), (__bf16)(av[3] + bias)};
          *(bf16x4*)(smc + ((cl * 512 + tk * 2) ^ ((cl & 7) << 4))) = pk;
        }
    }
  __syncthreads();

  // read rows of Ts (token-contiguous) -> scatter to vt[(bh*64+dl)*VSTRIDE + tok]
  // FULL coverage: 256 cols x 32 chunks(16B) = 8192 reads over 512 threads = 16 iters
  // (round-0 bug: 8 iters / ch=g&15 only covered tokens 0..127 -> absmax 0.448)
  #pragma unroll
  for (int it = 0; it < 16; ++it) {
    int g = it * 512 + tid;          // 0..8191: 256 cols x 32 chunks
    int cl = g >> 5, ch = g & 31;
    bf16x8 vv = *(const bf16x8*)(smc + ((cl * 512 + ch * 16) ^ ((cl & 7) << 4)));
    int col = n0loc + cl;
    int head = col >> 6, dl = col & 63;
    #pragma unroll
    for (int j = 0; j < 8; ++j) {
      int m = m0 + ch * 8 + j;
      if (m < Mdim) {
        int bb = m / 577, tok = m % 577;
        vt[((size_t)(bb * 12 + head) * 64 + dl) * VSTRIDE + tok] = vv[j];
      }
    }
  }
}

// ---------------- kernel 2: flash attention (softmax-lite) -------------------
__global__ __launch_bounds__(256) void attn_kernel(const __bf16* __restrict__ q,
                                                   const __bf16* __restrict__ k,
                                                   const __bf16* __restrict__ vt,
                                                   __bf16* __restrict__ ao) {
  __shared__ __bf16 qs[4096];
  __shared__ __bf16 ks[4096];
  __shared__ __bf16 vs[4096];
  __shared__ __bf16 ps[64 * 72];   // P strip, padded stride 72 (16B-aligned rows)

  // XCD swizzle: all 10 q-tiles of one (b,h) on one XCD -> K/V L2-resident
  const int x8 = blockIdx.x & 7;
  const int rest = blockIdx.x >> 3;
  const int qt = rest % 10;
  const int bh = (rest / 10) * 8 + x8;

  const int t = threadIdx.x;
  const int lane = t & 63, w = t >> 6;
  const int quad = lane >> 4, l16 = lane & 15;

  const __bf16* qbase = q + (size_t)bh * 577 * 64;
  const __bf16* kbase = k + (size_t)bh * 577 * 64;
  const __bf16* vbase = vt + (size_t)bh * 64 * VSTRIDE;

  // stage q tile once: 512 groups of 16B (rows >=577 read poison, discarded)
  #pragma unroll
  for (int p = 0; p < 2; ++p) {
    int g = p * 256 + t;
    int d8 = g >> 6, tok = g & 63;
    gl_lds16(qbase + (size_t)(qt * 64 + tok) * 64 + d8 * 8, qs + (size_t)g * 8);
  }

  f32x4 O[4]; const f32x4 fz = {0.f, 0.f, 0.f, 0.f};
  for (int i = 0; i < 4; ++i) O[i] = fz;
  float l_part[4] = {0.f, 0.f, 0.f, 0.f};

  for (int kt = 0; kt < 10; ++kt) {
    __syncthreads();   // previous tile's consumers done before restaging
    #pragma unroll
    for (int p = 0; p < 2; ++p) {
      int g = p * 256 + t;
      int d8 = g >> 6, tok = g & 63;
      gl_lds16(kbase + (size_t)(kt * 64 + tok) * 64 + d8 * 8, ks + (size_t)g * 8);
      gl_lds16(vbase + (size_t)(g & 63) * VSTRIDE + kt * 64 + (g >> 6) * 8, vs + (size_t)g * 8);
    }
    __syncthreads();   // staging drained (vmcnt(0) before barrier)

    // S = q k^T  (q pre-scaled by 0.125*log2e)
    f32x4 S[4]; for (int i = 0; i < 4; ++i) S[i] = fz;
    #pragma unroll
    for (int step = 0; step < 2; ++step) {
      bf16x8 a = *(const bf16x8*)(qs + (size_t)((step * 4 + quad) * 64 + w * 16 + l16) * 8);
      #pragma unroll
      for (int nt = 0; nt < 4; ++nt) {
        bf16x8 b = *(const bf16x8*)(ks + (size_t)((step * 4 + quad) * 64 + nt * 16 + l16) * 8);
        S[nt] = __builtin_amdgcn_mfma_f32_16x16x32_bf16(a, b, S[nt], 0, 0, 0);
      }
    }

    // mask invalid keys (only kt==9: 577 = 9*64 + 1); exp2(-1e30) -> 0
    int kv_left = 577 - kt * 64;
    if (kv_left < 64) {
      #pragma unroll
      for (int nt = 0; nt < 4; ++nt) {
        int c = nt * 16 + l16;
        if (c >= kv_left) { S[nt][0] = -1e30f; S[nt][1] = -1e30f; S[nt][2] = -1e30f; S[nt][3] = -1e30f; }
      }
    }

    // softmax-lite: exp2, per-lane l accumulation, P -> LDS (A-layout via ps)
    #pragma unroll
    for (int r = 0; r < 4; ++r) {
      #pragma unroll
      for (int nt = 0; nt < 4; ++nt) {
        float e = exp2f(S[nt][r]);
        l_part[r] += e;
        ps[(size_t)(w * 16 + quad * 4 + r) * 72 + nt * 16 + l16] = (__bf16)e;
      }
    }

    // O += P @ V   (P strip is wave-private; in-wave DS ordering covers w->r)
    #pragma unroll
    for (int step = 0; step < 2; ++step) {
      bf16x8 a = *(const bf16x8*)(ps + (size_t)(w * 16 + l16) * 72 + step * 32 + quad * 8);
      #pragma unroll
      for (int dt = 0; dt < 4; ++dt) {
        bf16x8 b = *(const bf16x8*)(vs + (size_t)((step * 4 + quad) * 64 + dt * 16 + l16) * 8);
        O[dt] = __builtin_amdgcn_mfma_f32_16x16x32_bf16(a, b, O[dt], 0, 0, 0);
      }
    }
  }

  // epilogue: reduce l across the 16 col-lanes, normalize, write ao[B*N, C]
  const int bb = bh / 12, hh = bh % 12;
  const int qrow0 = qt * 64 + w * 16 + quad * 4;
  #pragma unroll
  for (int r = 0; r < 4; ++r) {
    float l = l_part[r];
    l += __shfl_xor(l, 1); l += __shfl_xor(l, 2);
    l += __shfl_xor(l, 4); l += __shfl_xor(l, 8);
    int row = qrow0 + r;
    if (row < 577) {
      float inv = 1.f / l;
      size_t base = ((size_t)(bb * 577 + row)) * 768 + hh * 64;
      #pragma unroll
      for (int dt = 0; dt < 4; ++dt)
        ao[base + dt * 16 + l16] = (__bf16)(O[dt][r] * inv);
    }
  }
}

// ---------------- kernel 3: proj GEMM + bias -> fp32 out ---------------------
__global__ __launch_bounds__(512, 2) void proj_kernel(const __bf16* __restrict__ ao,
                                                      const __bf16* __restrict__ wprojT,
                                                      const float* __restrict__ b_proj,
                                                      float* __restrict__ out) {
  __shared__ __bf16 sm[65536];
  const int nb = blockIdx.x % 3, mb = blockIdx.x / 3;
  const int n0 = nb * 256, m0 = mb * 256;

  f32x4 acc[2][4][2][2];
  const f32x4 fz = {0.f, 0.f, 0.f, 0.f};
  #pragma unroll
  for (int i = 0; i < 2; ++i)
    #pragma unroll
    for (int j = 0; j < 4; ++j)
      #pragma unroll
      for (int u = 0; u < 2; ++u)
        #pragma unroll
        for (int v = 0; v < 2; ++v) acc[i][j][u][v] = fz;

  gemm256_core(ao, wprojT, m0, n0, sm, sm + 32768, acc);

  const int lane = threadIdx.x & 63, w = threadIdx.x >> 6;
  const int quad = lane >> 4, l16 = lane & 15;
  const int wm = w >> 2, wn = w & 3;

  #pragma unroll
  for (int qi = 0; qi < 2; ++qi)
    #pragma unroll
    for (int mf = 0; mf < 4; ++mf) {
      int mbase = m0 + qi * 128 + wm * 64 + mf * 16 + quad * 4;
      #pragma unroll
      for (int qj = 0; qj < 2; ++qj)
        #pragma unroll
        for (int nf = 0; nf < 2; ++nf) {
          int col = n0 + qj * 128 + wn * 32 + nf * 16 + l16;
          float bias = b_proj[col];
          #pragma unroll
          for (int r = 0; r < 4; ++r) {
            int m = mbase + r;
            if (m < Mdim) out[(size_t)m * 768 + col] = acc[qi][mf][qj][nf][r] + bias;
          }
        }
    }
}

// ---------------- launch -----------------------------------------------------
extern "C" void kernel_launch(void* const* d_in, const int* in_sizes, int n_in,
                              void* d_out, int out_size, void* d_ws, size_t ws_size,
                              hipStream_t stream) {
  const float* x      = (const float*)d_in[0];
  const float* w_qkv  = (const float*)d_in[1];
  const float* b_qkv  = (const float*)d_in[2];
  const float* w_proj = (const float*)d_in[3];
  const float* b_proj = (const float*)d_in[4];
  const float* rsn    = (const float*)d_in[5];
  const float* rcs    = (const float*)d_in[6];
  float* out = (float*)d_out;

  // workspace layout (bf16 elements); ao aliases x_bf (x consumed before attn)
  constexpr size_t QK_E = (size_t)Bdim * Hdim * Ndim * Ddim;      // 14,180,352
  constexpr size_t VT_E = (size_t)Bdim * Hdim * Ddim * VSTRIDE;   // 15,728,640
  constexpr size_t AO_E = (size_t)Mdim * Cdim;                    // 14,180,352
  __bf16* q      = (__bf16*)d_ws;
  __bf16* k      = q + QK_E;
  __bf16* vt     = k + QK_E;
  __bf16* ao     = vt + VT_E;        // also holds x_bf before attn runs
  __bf16* xb     = ao;
  __bf16* wqkvT  = ao + AO_E;
  __bf16* wprojT = wqkvT + (size_t)2304 * 768;
  // total: ~121 MB

  f32_to_bf16<<<13848, 256, 0, stream>>>((const float4*)x, (bf16x4*)xb,
                                         (int)(AO_E / 4));
  transpose_f32_bf16<<<dim3(36, 12), 256, 0, stream>>>(w_qkv, wqkvT, 768, 2304, 1);
  transpose_f32_bf16<<<dim3(12, 12), 256, 0, stream>>>(w_proj, wprojT, 768, 768, 0);
  qk_kernel<<<73 * 6, 512, 0, stream>>>(xb, wqkvT, b_qkv, rsn, rcs, q, k);
  v_kernel<<<73 * 3, 512, 0, stream>>>(xb, wqkvT, b_qkv, vt);
  attn_kernel<<<3840, 256, 0, stream>>>(q, k, vt, ao);
  proj_kernel<<<73 * 3, 512, 0, stream>>>(ao, wprojT, b_proj, out);
}

// Round 4
// 436.150 us; speedup vs baseline: 1.0887x; 1.0593x over previous
//
#include <hip/hip_runtime.h>

#define Bdim 32
#define Ndim 577
#define Cdim 768
#define Hdim 12
#define Ddim 64
#define Mdim (Bdim*Ndim)   // 18464
#define VSTRIDE 640        // padded token stride for v^T (kt=9 staging stays in-bounds)
#define TSTRIDE 152        // v-transpose LDS tile token stride (304B rows, 16B-aligned)
#define QSCALE 0.18033688f // 0.125 * log2(e): attn uses exp2, so fold log2e into q
#define MGRP 19            // ceil(145/8) m-strip groups for XCD swizzle

typedef __attribute__((ext_vector_type(4))) float f32x4;
typedef __attribute__((ext_vector_type(8))) __bf16 bf16x8;
typedef __attribute__((ext_vector_type(4))) __bf16 bf16x4;

__device__ __forceinline__ void gl_lds16(const __bf16* g, __bf16* l) {
  __builtin_amdgcn_global_load_lds((const __attribute__((address_space(1))) void*)g,
                                   (__attribute__((address_space(3))) void*)l, 16, 0, 0);
}

// ---------------- fp32 -> bf16 convert (vectorized) --------------------------
__global__ __launch_bounds__(256) void f32_to_bf16(const float4* __restrict__ in,
                                                   bf16x4* __restrict__ out, int n4) {
  int i = blockIdx.x * 256 + threadIdx.x;
  if (i < n4) {
    float4 v = in[i];
    bf16x4 o = {(__bf16)v.x, (__bf16)v.y, (__bf16)v.z, (__bf16)v.w};
    out[i] = o;
  }
}

// ------------- transpose + downcast: in fp32 [R][Cc] -> out bf16 [Cc][R] -----
__global__ __launch_bounds__(256) void transpose_f32_bf16(const float* __restrict__ in,
                                                          __bf16* __restrict__ out,
                                                          int R, int Cc) {
  __shared__ float tile[64][65];
  int bx = blockIdx.x * 64;           // col base (Cc dim)
  int by = blockIdx.y * 64;           // row base (R dim)
  int tx = threadIdx.x & 63, ty = threadIdx.x >> 6;
  for (int i = ty; i < 64; i += 4) {
    int r = by + i, c = bx + tx;
    tile[i][tx] = (r < R && c < Cc) ? in[(size_t)r * Cc + c] : 0.f;
  }
  __syncthreads();
  for (int i = ty; i < 64; i += 4) {
    int r = bx + i, c = by + tx;      // out is [Cc][R]
    if (r < Cc && c < R) out[(size_t)r * R + c] = (__bf16)tile[tx][i];
  }
}

// -------- shared GEMM-BT mainloop: C[128x128] tile, K=768, BK=64 -------------
// Proven r-1 structure (126us qk): 2 barriers/K-tile, 5 blocks/CU TLP hides the
// staging wait (m114 mechanism). Pipeline variants (r2 dbuf, r3 4-phase) both
// regressed by trading occupancy for structure -- do not re-try without new data.
__device__ __forceinline__ void gemm_bt_core(const __bf16* __restrict__ A,
                                             const __bf16* __restrict__ BT,
                                             int m0, int n0,
                                             __bf16* As, __bf16* Bs,
                                             f32x4 acc[4][4]) {
  const int t = threadIdx.x;
  const int lane = t & 63, w = t >> 6;
  const int quad = lane >> 4, l16 = lane & 15;
  const int wm = w >> 1, wn = w & 1;

  for (int k0 = 0; k0 < 768; k0 += 64) {
    __syncthreads();
    #pragma unroll
    for (int e = 0; e < 4; ++e) {
      int h = e >> 1;
      int j = ((e & 1) << 2) | w;                 // row-group 0..7
      int row = j * 16 + (lane >> 2);             // 0..127
      int col = k0 + h * 32 + (lane & 3) * 8;
      int ar = m0 + row; if (ar > Mdim - 1) ar = Mdim - 1;   // M tail clamp
      __bf16* dstA = As + h * 4096 + j * 512 + lane * 8;     // uniform + lane*16B
      __bf16* dstB = Bs + h * 4096 + j * 512 + lane * 8;
      gl_lds16(A  + (size_t)ar * 768 + col, dstA);
      gl_lds16(BT + (size_t)(n0 + row) * 768 + col, dstB);
    }
    __syncthreads();
    #pragma unroll
    for (int s = 0; s < 2; ++s) {
      bf16x8 a[4], b[4];
      #pragma unroll
      for (int i = 0; i < 4; ++i) {
        a[i] = *(const bf16x8*)(As + s * 4096 + (wm * 64 + i * 16 + l16) * 32 + quad * 8);
        b[i] = *(const bf16x8*)(Bs + s * 4096 + (wn * 64 + i * 16 + l16) * 32 + quad * 8);
      }
      #pragma unroll
      for (int mt = 0; mt < 4; ++mt)
        #pragma unroll
        for (int nt = 0; nt < 4; ++nt)
          acc[mt][nt] = __builtin_amdgcn_mfma_f32_16x16x32_bf16(a[mt], b[nt], acc[mt][nt], 0, 0, 0);
    }
  }
}

// XCD swizzle decode: all nb n-blocks of one m-strip land on one XCD
// (strip % 8 == linear % 8 under round-robin dispatch). Returns false for pads.
__device__ __forceinline__ bool xcd_decode(int lin, int nb, int mb, int& n, int& m) {
  int x8 = lin & 7;
  int rest = lin >> 3;
  n = rest % nb;
  int mg = rest / nb;
  m = mg * 8 + x8;
  return m < mb;
}

// ---------------- kernel 1a: Q/K GEMM + bias + RoPE (cols 0..1535) -----------
__global__ __launch_bounds__(256) void qk_kernel(const __bf16* __restrict__ x,
                                                 const __bf16* __restrict__ wqkvT,
                                                 const float* __restrict__ b_qkv,
                                                 const float* __restrict__ rs,
                                                 const float* __restrict__ rc,
                                                 __bf16* __restrict__ q,
                                                 __bf16* __restrict__ k) {
  __shared__ __bf16 As[2 * 128 * 32];
  __shared__ __bf16 Bs[2 * 128 * 32];
  int nb, mbk;
  if (!xcd_decode(blockIdx.x, 12, 145, nb, mbk)) return;
  const int n0 = nb * 128, m0 = mbk * 128;

  f32x4 acc[4][4];
  const f32x4 fz = {0.f, 0.f, 0.f, 0.f};
  for (int i = 0; i < 4; ++i) for (int j = 0; j < 4; ++j) acc[i][j] = fz;
  gemm_bt_core(x, wqkvT, m0, n0, As, Bs, acc);

  const int lane = threadIdx.x & 63, w = threadIdx.x >> 6;
  const int quad = lane >> 4, l16 = lane & 15;
  const int wm = w >> 1, wn = w & 1;
  const int colbase = n0 + wn * 64;          // 64-aligned -> one (matrix, head)
  const int matrix = colbase / 768;          // 0=q 1=k
  const int head = (colbase % 768) / 64;

  #pragma unroll
  for (int mt = 0; mt < 4; ++mt) {
    int mbase = m0 + wm * 64 + mt * 16 + quad * 4;
    #pragma unroll
    for (int r = 0; r < 4; ++r) {
      int m = mbase + r;
      if (m >= Mdim) continue;
      int bb = m / 577, tok = m % 577;
      #pragma unroll
      for (int nt = 0; nt < 4; ++nt) {
        int d = nt * 16 + l16;
        float val = acc[mt][nt][r] + b_qkv[colbase + d];
        if (tok > 0) {
          float partner = acc[mt][nt ^ 2][r] + b_qkv[colbase + (d ^ 32)];
          float sn = rs[(size_t)(tok - 1) * 64 + d];
          float cs = rc[(size_t)(tok - 1) * 64 + d];
          float rot = (d < 32) ? -partner : partner;
          val = val * cs + rot * sn;
        }
        __bf16* dst;
        if (matrix == 0) { val *= QSCALE; dst = q; } else dst = k;
        dst[((size_t)(bb * 12 + head) * 577 + tok) * 64 + d] = (__bf16)val;
      }
    }
  }
}

// ---------------- kernel 1b: V GEMM + bias + LDS-transpose (cols 1536..2303) -
__global__ __launch_bounds__(256) void v_kernel(const __bf16* __restrict__ x,
                                                const __bf16* __restrict__ wqkvT,
                                                const float* __restrict__ b_qkv,
                                                __bf16* __restrict__ vt) {
  __shared__ __bf16 As[2 * 128 * 32];
  __shared__ __bf16 Bs[2 * 128 * 32];
  __shared__ __bf16 Ts[64 * TSTRIDE];   // v-transpose half-tile [d-local][token]
  int nb, mbk;
  if (!xcd_decode(blockIdx.x, 6, 145, nb, mbk)) return;
  const int n0 = 1536 + nb * 128, m0 = mbk * 128;

  f32x4 acc[4][4];
  const f32x4 fz = {0.f, 0.f, 0.f, 0.f};
  for (int i = 0; i < 4; ++i) for (int j = 0; j < 4; ++j) acc[i][j] = fz;
  gemm_bt_core(x, wqkvT, m0, n0, As, Bs, acc);

  const int t = threadIdx.x;
  const int lane = t & 63, w = t >> 6;
  const int quad = lane >> 4, l16 = lane & 15;
  const int wm = w >> 1, wn = w & 1;
  const int colbase = n0 + wn * 64;

  #pragma unroll
  for (int h = 0; h < 2; ++h) {
    __syncthreads();
    if (wn == h) {
      #pragma unroll
      for (int mt = 0; mt < 4; ++mt) {
        int tokbase = wm * 64 + mt * 16 + quad * 4;
        #pragma unroll
        for (int r = 0; r < 4; ++r) {
          #pragma unroll
          for (int nt = 0; nt < 4; ++nt) {
            int dl = nt * 16 + l16;
            Ts[dl * TSTRIDE + tokbase + r] =
                (__bf16)(acc[mt][nt][r] + b_qkv[colbase + dl]);
          }
        }
      }
    }
    __syncthreads();
    int hh = (n0 + h * 64 - 1536) / 64;    // head for this half
    #pragma unroll
    for (int it = 0; it < 4; ++it) {
      int c = it * 256 + t;
      int dl = c >> 4, chunk = c & 15;
      bf16x8 vv = *(const bf16x8*)(Ts + dl * TSTRIDE + chunk * 8);
      #pragma unroll
      for (int j = 0; j < 8; ++j) {
        int m = m0 + chunk * 8 + j;
        if (m < Mdim) {
          int bb = m / 577, tok = m % 577;
          vt[((size_t)(bb * 12 + hh) * 64 + dl) * VSTRIDE + tok] = vv[j];
        }
      }
    }
  }
}

// ---------------- kernel 2: flash attention (softmax-lite) -------------------
// r4 change (T14): K/V staged via register prefetch + ds_write instead of
// global_load_lds. The per-tile barrier chain no longer contains an HBM wait:
// loads for tile kt+1 fly during compute of tile kt; the ds_write between
// barriers is ~128 cycles of LDS. Layout in ks/vs is bit-identical to before.
// T5: setprio(1) around the QK and PV MFMA clusters (independent blocks at
// staggered phases -> scheduler has real arbitration to do).
__global__ __launch_bounds__(256) void attn_kernel(const __bf16* __restrict__ q,
                                                   const __bf16* __restrict__ k,
                                                   const __bf16* __restrict__ vt,
                                                   __bf16* __restrict__ ao) {
  __shared__ __bf16 qs[4096];
  __shared__ __bf16 ks[4096];
  __shared__ __bf16 vs[4096];
  __shared__ __bf16 ps[64 * 72];   // P strip, padded stride 72 (16B-aligned rows)

  // XCD swizzle: all 10 q-tiles of one (b,h) on one XCD -> K/V L2-resident
  const int x8 = blockIdx.x & 7;
  const int rest = blockIdx.x >> 3;
  const int qt = rest % 10;
  const int bh = (rest / 10) * 8 + x8;

  const int t = threadIdx.x;
  const int lane = t & 63, w = t >> 6;
  const int quad = lane >> 4, l16 = lane & 15;

  const __bf16* qbase = q + (size_t)bh * 577 * 64;
  const __bf16* kbase = k + (size_t)bh * 577 * 64;
  const __bf16* vbase = vt + (size_t)bh * 64 * VSTRIDE;

  // stage q tile once: 512 groups of 16B (rows >=577 read poison, discarded)
  #pragma unroll
  for (int p = 0; p < 2; ++p) {
    int g = p * 256 + t;
    int d8 = g >> 6, tok = g & 63;
    gl_lds16(qbase + (size_t)(qt * 64 + tok) * 64 + d8 * 8, qs + (size_t)g * 8);
  }

  // K/V tile 0 -> registers (same (g -> d8,tok) mapping the LDS layout uses)
  bf16x8 kreg[2], vreg[2];
  #pragma unroll
  for (int p = 0; p < 2; ++p) {
    int g = p * 256 + t;
    kreg[p] = *(const bf16x8*)(kbase + (size_t)(g & 63) * 64 + (g >> 6) * 8);
    vreg[p] = *(const bf16x8*)(vbase + (size_t)(g & 63) * VSTRIDE + (g >> 6) * 8);
  }

  f32x4 O[4]; const f32x4 fz = {0.f, 0.f, 0.f, 0.f};
  for (int i = 0; i < 4; ++i) O[i] = fz;
  float l_part[4] = {0.f, 0.f, 0.f, 0.f};

  for (int kt = 0; kt < 10; ++kt) {
    __syncthreads();   // all readers of ks/vs (tile kt-1) done; kt=0: drains q-stage vmcnt
    #pragma unroll
    for (int p = 0; p < 2; ++p) {
      int g = p * 256 + t;
      *(bf16x8*)(ks + (size_t)g * 8) = kreg[p];   // k: [d8][tok][8]
      *(bf16x8*)(vs + (size_t)g * 8) = vreg[p];   // v: [tok8][d][8]
    }
    __syncthreads();   // ds_writes visible to all waves

    // issue next tile's loads NOW; they complete under this tile's compute
    if (kt < 9) {
      #pragma unroll
      for (int p = 0; p < 2; ++p) {
        int g = p * 256 + t;
        kreg[p] = *(const bf16x8*)(kbase + (size_t)((kt + 1) * 64 + (g & 63)) * 64 + (g >> 6) * 8);
        vreg[p] = *(const bf16x8*)(vbase + (size_t)(g & 63) * VSTRIDE + (kt + 1) * 64 + (g >> 6) * 8);
      }
      __builtin_amdgcn_sched_barrier(0);   // pin load issue before compute
    }

    // S = q k^T  (q pre-scaled by 0.125*log2e)
    f32x4 S[4]; for (int i = 0; i < 4; ++i) S[i] = fz;
    __builtin_amdgcn_s_setprio(1);
    #pragma unroll
    for (int step = 0; step < 2; ++step) {
      bf16x8 a = *(const bf16x8*)(qs + (size_t)((step * 4 + quad) * 64 + w * 16 + l16) * 8);
      #pragma unroll
      for (int nt = 0; nt < 4; ++nt) {
        bf16x8 b = *(const bf16x8*)(ks + (size_t)((step * 4 + quad) * 64 + nt * 16 + l16) * 8);
        S[nt] = __builtin_amdgcn_mfma_f32_16x16x32_bf16(a, b, S[nt], 0, 0, 0);
      }
    }
    __builtin_amdgcn_s_setprio(0);

    // mask invalid keys (only kt==9: 577 = 9*64 + 1); exp2(-1e30) -> 0
    int kv_left = 577 - kt * 64;
    if (kv_left < 64) {
      #pragma unroll
      for (int nt = 0; nt < 4; ++nt) {
        int c = nt * 16 + l16;
        if (c >= kv_left) { S[nt][0] = -1e30f; S[nt][1] = -1e30f; S[nt][2] = -1e30f; S[nt][3] = -1e30f; }
      }
    }

    // softmax-lite: exp2, per-lane l accumulation, P -> LDS (A-layout via ps)
    #pragma unroll
    for (int r = 0; r < 4; ++r) {
      #pragma unroll
      for (int nt = 0; nt < 4; ++nt) {
        float e = exp2f(S[nt][r]);
        l_part[r] += e;
        ps[(size_t)(w * 16 + quad * 4 + r) * 72 + nt * 16 + l16] = (__bf16)e;
      }
    }

    // O += P @ V   (P strip is wave-private; in-wave DS ordering covers w->r)
    __builtin_amdgcn_s_setprio(1);
    #pragma unroll
    for (int step = 0; step < 2; ++step) {
      bf16x8 a = *(const bf16x8*)(ps + (size_t)(w * 16 + l16) * 72 + step * 32 + quad * 8);
      #pragma unroll
      for (int dt = 0; dt < 4; ++dt) {
        bf16x8 b = *(const bf16x8*)(vs + (size_t)((step * 4 + quad) * 64 + dt * 16 + l16) * 8);
        O[dt] = __builtin_amdgcn_mfma_f32_16x16x32_bf16(a, b, O[dt], 0, 0, 0);
      }
    }
    __builtin_amdgcn_s_setprio(0);
  }

  // epilogue: reduce l across the 16 col-lanes, normalize, write ao[B*N, C]
  const int bb = bh / 12, hh = bh % 12;
  const int qrow0 = qt * 64 + w * 16 + quad * 4;
  #pragma unroll
  for (int r = 0; r < 4; ++r) {
    float l = l_part[r];
    l += __shfl_xor(l, 1); l += __shfl_xor(l, 2);
    l += __shfl_xor(l, 4); l += __shfl_xor(l, 8);
    int row = qrow0 + r;
    if (row < 577) {
      float inv = 1.f / l;
      size_t base = ((size_t)(bb * 577 + row)) * 768 + hh * 64;
      #pragma unroll
      for (int dt = 0; dt < 4; ++dt)
        ao[base + dt * 16 + l16] = (__bf16)(O[dt][r] * inv);
    }
  }
}

// ---------------- kernel 3: proj GEMM + bias -> fp32 out ---------------------
__global__ __launch_bounds__(256) void proj_kernel(const __bf16* __restrict__ ao,
                                                   const __bf16* __restrict__ wprojT,
                                                   const float* __restrict__ b_proj,
                                                   float* __restrict__ out) {
  __shared__ __bf16 As[2 * 128 * 32];
  __shared__ __bf16 Bs[2 * 128 * 32];
  int nb, mbk;
  if (!xcd_decode(blockIdx.x, 6, 145, nb, mbk)) return;
  const int n0 = nb * 128, m0 = mbk * 128;

  f32x4 acc[4][4];
  const f32x4 fz = {0.f, 0.f, 0.f, 0.f};
  for (int i = 0; i < 4; ++i) for (int j = 0; j < 4; ++j) acc[i][j] = fz;
  gemm_bt_core(ao, wprojT, m0, n0, As, Bs, acc);

  const int lane = threadIdx.x & 63, w = threadIdx.x >> 6;
  const int quad = lane >> 4, l16 = lane & 15;
  const int wm = w >> 1, wn = w & 1;
  const int colbase = n0 + wn * 64;

  #pragma unroll
  for (int mt = 0; mt < 4; ++mt) {
    int mbase = m0 + wm * 64 + mt * 16 + quad * 4;
    #pragma unroll
    for (int r = 0; r < 4; ++r) {
      int m = mbase + r;
      if (m >= Mdim) continue;
      #pragma unroll
      for (int nt = 0; nt < 4; ++nt) {
        int c = colbase + nt * 16 + l16;
        out[(size_t)m * 768 + c] = acc[mt][nt][r] + b_proj[c];
      }
    }
  }
}

// ---------------- launch -----------------------------------------------------
extern "C" void kernel_launch(void* const* d_in, const int* in_sizes, int n_in,
                              void* d_out, int out_size, void* d_ws, size_t ws_size,
                              hipStream_t stream) {
  const float* x      = (const float*)d_in[0];
  const float* w_qkv  = (const float*)d_in[1];
  const float* b_qkv  = (const float*)d_in[2];
  const float* w_proj = (const float*)d_in[3];
  const float* b_proj = (const float*)d_in[4];
  const float* rsn    = (const float*)d_in[5];
  const float* rcs    = (const float*)d_in[6];
  float* out = (float*)d_out;

  // workspace layout (bf16 elements); ao aliases x_bf (x consumed before attn)
  constexpr size_t QK_E = (size_t)Bdim * Hdim * Ndim * Ddim;      // 14,180,352
  constexpr size_t VT_E = (size_t)Bdim * Hdim * Ddim * VSTRIDE;   // 15,728,640
  constexpr size_t AO_E = (size_t)Mdim * Cdim;                    // 14,180,352
  __bf16* q      = (__bf16*)d_ws;
  __bf16* k      = q + QK_E;
  __bf16* vt     = k + QK_E;
  __bf16* ao     = vt + VT_E;        // also holds x_bf before attn runs
  __bf16* xb     = ao;
  __bf16* wqkvT  = ao + AO_E;
  __bf16* wprojT = wqkvT + (size_t)2304 * 768;
  // total: ~121 MB

  f32_to_bf16<<<13848, 256, 0, stream>>>((const float4*)x, (bf16x4*)xb,
                                         (int)(AO_E / 4));
  transpose_f32_bf16<<<dim3(36, 12), 256, 0, stream>>>(w_qkv, wqkvT, 768, 2304);
  transpose_f32_bf16<<<dim3(12, 12), 256, 0, stream>>>(w_proj, wprojT, 768, 768);
  qk_kernel<<<8 * MGRP * 12, 256, 0, stream>>>(xb, wqkvT, b_qkv, rsn, rcs, q, k);
  v_kernel<<<8 * MGRP * 6, 256, 0, stream>>>(xb, wqkvT, b_qkv, vt);
  attn_kernel<<<3840, 256, 0, stream>>>(q, k, vt, ao);
  proj_kernel<<<8 * MGRP * 6, 256, 0, stream>>>(ao, wprojT, b_proj, out);
}

// Round 5
// 432.332 us; speedup vs baseline: 1.0983x; 1.0088x over previous
//
#include <hip/hip_runtime.h>

#define Bdim 32
#define Ndim 577
#define Cdim 768
#define Hdim 12
#define Ddim 64
#define Mdim (Bdim*Ndim)   // 18464
#define VSTRIDE 640        // padded token stride for v^T (kt=9 staging stays in-bounds)
#define TSTRIDE 152        // v-transpose LDS tile token stride (304B rows, 16B-aligned)
#define QSCALE 0.18033688f // 0.125 * log2(e): attn uses exp2, so fold log2e into q
#define MGRP 19            // ceil(145/8) m-strip groups for XCD swizzle

typedef __attribute__((ext_vector_type(4))) float f32x4;
typedef __attribute__((ext_vector_type(8))) __bf16 bf16x8;
typedef __attribute__((ext_vector_type(4))) __bf16 bf16x4;

__device__ __forceinline__ void gl_lds16(const __bf16* g, __bf16* l) {
  __builtin_amdgcn_global_load_lds((const __attribute__((address_space(1))) void*)g,
                                   (__attribute__((address_space(3))) void*)l, 16, 0, 0);
}

// ---------------- fp32 -> bf16 convert (vectorized) --------------------------
__global__ __launch_bounds__(256) void f32_to_bf16(const float4* __restrict__ in,
                                                   bf16x4* __restrict__ out, int n4) {
  int i = blockIdx.x * 256 + threadIdx.x;
  if (i < n4) {
    float4 v = in[i];
    bf16x4 o = {(__bf16)v.x, (__bf16)v.y, (__bf16)v.z, (__bf16)v.w};
    out[i] = o;
  }
}

// ------------- transpose + downcast: in fp32 [R][Cc] -> out bf16 [Cc][R] -----
// (used for w_proj only; w_qkv goes to fragment-major via transpose_f32_wfrag)
__global__ __launch_bounds__(256) void transpose_f32_bf16(const float* __restrict__ in,
                                                          __bf16* __restrict__ out,
                                                          int R, int Cc) {
  __shared__ float tile[64][65];
  int bx = blockIdx.x * 64;           // col base (Cc dim)
  int by = blockIdx.y * 64;           // row base (R dim)
  int tx = threadIdx.x & 63, ty = threadIdx.x >> 6;
  for (int i = ty; i < 64; i += 4) {
    int r = by + i, c = bx + tx;
    tile[i][tx] = (r < R && c < Cc) ? in[(size_t)r * Cc + c] : 0.f;
  }
  __syncthreads();
  for (int i = ty; i < 64; i += 4) {
    int r = bx + i, c = by + tx;      // out is [Cc][R]
    if (r < Cc && c < R) out[(size_t)r * R + c] = (__bf16)tile[tx][i];
  }
}

// ---- w_qkv fp32 [768][2304] -> fragment-major bf16 wf[n/16][k/8][16][8] -----
// wf element (n,k) = w_qkv[k][n]; a wave's MFMA B-frag load (16 n-rows x 8 k)
// becomes one contiguous, fully-coalesced 1KB global_load_dwordx4 per frag.
__global__ __launch_bounds__(256) void transpose_f32_wfrag(const float* __restrict__ in,
                                                           __bf16* __restrict__ out) {
  __shared__ float tile[64][65];      // [k-local][n-local]
  int bx = blockIdx.x * 64;           // n base (0..2304)
  int by = blockIdx.y * 64;           // k base (0..768)
  int tx = threadIdx.x & 63, ty = threadIdx.x >> 6;
  #pragma unroll
  for (int i = ty; i < 64; i += 4)
    tile[i][tx] = in[(size_t)(by + i) * 2304 + bx + tx];
  __syncthreads();
  #pragma unroll
  for (int it = 0; it < 2; ++it) {
    int idx = it * 256 + threadIdx.x; // 0..511 = 64 n x 8 k-chunks
    int nl = idx & 63, kc = idx >> 6;
    bf16x8 o;
    #pragma unroll
    for (int j = 0; j < 8; ++j) o[j] = (__bf16)tile[kc * 8 + j][nl];
    int n = bx + nl, kk = by + kc * 8;
    *(bf16x8*)(out + ((size_t)(n >> 4) * 96 + (kk >> 3)) * 128 + (n & 15) * 8) = o;
  }
}

// ======== split-pipe GEMM core (qk/v): A via LDS, B direct from L2 ===========
// r4 PMC: qk was 83% LDS-read-bound (5.35M b128 reads == SQ_LDS_BANK_CONFLICT,
// ~104us of LDS pipe at 12cyc/b128). Halve LDS traffic: B-frags load straight
// from the L2-resident frag-major weights (coalesced 1KB/wave/frag), issued at
// tile top so they fly under A-staging + barrier drain. LDS (A) and L1/L2 (B)
// pipes then serve fragments in parallel.
__device__ __forceinline__ void gemm_split_core(const __bf16* __restrict__ A,
                                                const __bf16* __restrict__ WF,
                                                int m0, int n0,
                                                __bf16* As, f32x4 acc[4][4]) {
  const int t = threadIdx.x;
  const int lane = t & 63, w = t >> 6;
  const int quad = lane >> 4, l16 = lane & 15;
  const int wm = w >> 1, wn = w & 1;
  const int nb16 = (n0 >> 4) + wn * 4;

  for (int k0 = 0; k0 < 768; k0 += 64) {
    __syncthreads();                  // prev tile's LDS consumers done
    // B frags (both k32-halves) from global; no LDS dependency -> in flight
    // during staging, drained by the pre-barrier vmcnt(0) below.
    bf16x8 b[2][4];
    #pragma unroll
    for (int s = 0; s < 2; ++s)
      #pragma unroll
      for (int i = 0; i < 4; ++i)
        b[s][i] = *(const bf16x8*)(WF +
            ((size_t)(nb16 + i) * 96 + (k0 >> 3) + s * 4 + quad) * 128 + l16 * 8);
    // stage A tile: 4 x gl_lds16 / thread (h 0..1 halves x j 0..7 row-groups)
    #pragma unroll
    for (int e = 0; e < 4; ++e) {
      int h = e >> 1;
      int j = ((e & 1) << 2) | w;
      int row = j * 16 + (lane >> 2);
      int col = k0 + h * 32 + (lane & 3) * 8;
      int ar = m0 + row; if (ar > Mdim - 1) ar = Mdim - 1;   // M tail clamp
      gl_lds16(A + (size_t)ar * 768 + col, As + h * 4096 + j * 512 + lane * 8);
    }
    __syncthreads();                  // A staged + b[] resident
    #pragma unroll
    for (int s = 0; s < 2; ++s) {
      bf16x8 a[4];
      #pragma unroll
      for (int i = 0; i < 4; ++i)
        a[i] = *(const bf16x8*)(As + s * 4096 + (wm * 64 + i * 16 + l16) * 32 + quad * 8);
      #pragma unroll
      for (int mt = 0; mt < 4; ++mt)
        #pragma unroll
        for (int nt = 0; nt < 4; ++nt)
          acc[mt][nt] = __builtin_amdgcn_mfma_f32_16x16x32_bf16(a[mt], b[s][nt], acc[mt][nt], 0, 0, 0);
    }
  }
}

// -------- proj keeps the proven both-in-LDS mainloop (A=ao is linear) --------
__device__ __forceinline__ void gemm_bt_core(const __bf16* __restrict__ A,
                                             const __bf16* __restrict__ BT,
                                             int m0, int n0,
                                             __bf16* As, __bf16* Bs,
                                             f32x4 acc[4][4]) {
  const int t = threadIdx.x;
  const int lane = t & 63, w = t >> 6;
  const int quad = lane >> 4, l16 = lane & 15;
  const int wm = w >> 1, wn = w & 1;

  for (int k0 = 0; k0 < 768; k0 += 64) {
    __syncthreads();
    #pragma unroll
    for (int e = 0; e < 4; ++e) {
      int h = e >> 1;
      int j = ((e & 1) << 2) | w;                 // row-group 0..7
      int row = j * 16 + (lane >> 2);             // 0..127
      int col = k0 + h * 32 + (lane & 3) * 8;
      int ar = m0 + row; if (ar > Mdim - 1) ar = Mdim - 1;   // M tail clamp
      __bf16* dstA = As + h * 4096 + j * 512 + lane * 8;     // uniform + lane*16B
      __bf16* dstB = Bs + h * 4096 + j * 512 + lane * 8;
      gl_lds16(A  + (size_t)ar * 768 + col, dstA);
      gl_lds16(BT + (size_t)(n0 + row) * 768 + col, dstB);
    }
    __syncthreads();
    #pragma unroll
    for (int s = 0; s < 2; ++s) {
      bf16x8 a[4], b[4];
      #pragma unroll
      for (int i = 0; i < 4; ++i) {
        a[i] = *(const bf16x8*)(As + s * 4096 + (wm * 64 + i * 16 + l16) * 32 + quad * 8);
        b[i] = *(const bf16x8*)(Bs + s * 4096 + (wn * 64 + i * 16 + l16) * 32 + quad * 8);
      }
      #pragma unroll
      for (int mt = 0; mt < 4; ++mt)
        #pragma unroll
        for (int nt = 0; nt < 4; ++nt)
          acc[mt][nt] = __builtin_amdgcn_mfma_f32_16x16x32_bf16(a[mt], b[nt], acc[mt][nt], 0, 0, 0);
    }
  }
}

// XCD swizzle decode: all nb n-blocks of one m-strip land on one XCD
// (strip % 8 == linear % 8 under round-robin dispatch). Returns false for pads.
__device__ __forceinline__ bool xcd_decode(int lin, int nb, int mb, int& n, int& m) {
  int x8 = lin & 7;
  int rest = lin >> 3;
  n = rest % nb;
  int mg = rest / nb;
  m = mg * 8 + x8;
  return m < mb;
}

// ---------------- kernel 1a: Q/K GEMM + bias + RoPE (cols 0..1535) -----------
__global__ __launch_bounds__(256) void qk_kernel(const __bf16* __restrict__ x,
                                                 const __bf16* __restrict__ wf,
                                                 const float* __restrict__ b_qkv,
                                                 const float* __restrict__ rs,
                                                 const float* __restrict__ rc,
                                                 __bf16* __restrict__ q,
                                                 __bf16* __restrict__ k) {
  __shared__ __bf16 As[2 * 128 * 32];
  int nb, mbk;
  if (!xcd_decode(blockIdx.x, 12, 145, nb, mbk)) return;
  const int n0 = nb * 128, m0 = mbk * 128;

  f32x4 acc[4][4];
  const f32x4 fz = {0.f, 0.f, 0.f, 0.f};
  for (int i = 0; i < 4; ++i) for (int j = 0; j < 4; ++j) acc[i][j] = fz;
  gemm_split_core(x, wf, m0, n0, As, acc);

  const int lane = threadIdx.x & 63, w = threadIdx.x >> 6;
  const int quad = lane >> 4, l16 = lane & 15;
  const int wm = w >> 1, wn = w & 1;
  const int colbase = n0 + wn * 64;          // 64-aligned -> one (matrix, head)
  const int matrix = colbase / 768;          // 0=q 1=k
  const int head = (colbase % 768) / 64;

  #pragma unroll
  for (int mt = 0; mt < 4; ++mt) {
    int mbase = m0 + wm * 64 + mt * 16 + quad * 4;
    #pragma unroll
    for (int r = 0; r < 4; ++r) {
      int m = mbase + r;
      if (m >= Mdim) continue;
      int bb = m / 577, tok = m % 577;
      #pragma unroll
      for (int nt = 0; nt < 4; ++nt) {
        int d = nt * 16 + l16;
        float val = acc[mt][nt][r] + b_qkv[colbase + d];
        if (tok > 0) {
          float partner = acc[mt][nt ^ 2][r] + b_qkv[colbase + (d ^ 32)];
          float sn = rs[(size_t)(tok - 1) * 64 + d];
          float cs = rc[(size_t)(tok - 1) * 64 + d];
          float rot = (d < 32) ? -partner : partner;
          val = val * cs + rot * sn;
        }
        __bf16* dst;
        if (matrix == 0) { val *= QSCALE; dst = q; } else dst = k;
        dst[((size_t)(bb * 12 + head) * 577 + tok) * 64 + d] = (__bf16)val;
      }
    }
  }
}

// ---------------- kernel 1b: V GEMM + bias + LDS-transpose (cols 1536..2303) -
__global__ __launch_bounds__(256) void v_kernel(const __bf16* __restrict__ x,
                                                const __bf16* __restrict__ wf,
                                                const float* __restrict__ b_qkv,
                                                __bf16* __restrict__ vt) {
  __shared__ __bf16 As[2 * 128 * 32];
  __shared__ __bf16 Ts[64 * TSTRIDE];   // v-transpose half-tile [d-local][token]
  int nb, mbk;
  if (!xcd_decode(blockIdx.x, 6, 145, nb, mbk)) return;
  const int n0 = 1536 + nb * 128, m0 = mbk * 128;

  f32x4 acc[4][4];
  const f32x4 fz = {0.f, 0.f, 0.f, 0.f};
  for (int i = 0; i < 4; ++i) for (int j = 0; j < 4; ++j) acc[i][j] = fz;
  gemm_split_core(x, wf, m0, n0, As, acc);

  const int t = threadIdx.x;
  const int lane = t & 63, w = t >> 6;
  const int quad = lane >> 4, l16 = lane & 15;
  const int wm = w >> 1, wn = w & 1;
  const int colbase = n0 + wn * 64;

  #pragma unroll
  for (int h = 0; h < 2; ++h) {
    __syncthreads();
    if (wn == h) {
      #pragma unroll
      for (int mt = 0; mt < 4; ++mt) {
        int tokbase = wm * 64 + mt * 16 + quad * 4;
        #pragma unroll
        for (int r = 0; r < 4; ++r) {
          #pragma unroll
          for (int nt = 0; nt < 4; ++nt) {
            int dl = nt * 16 + l16;
            Ts[dl * TSTRIDE + tokbase + r] =
                (__bf16)(acc[mt][nt][r] + b_qkv[colbase + dl]);
          }
        }
      }
    }
    __syncthreads();
    int hh = (n0 + h * 64 - 1536) / 64;    // head for this half
    #pragma unroll
    for (int it = 0; it < 4; ++it) {
      int c = it * 256 + t;
      int dl = c >> 4, chunk = c & 15;
      bf16x8 vv = *(const bf16x8*)(Ts + dl * TSTRIDE + chunk * 8);
      #pragma unroll
      for (int j = 0; j < 8; ++j) {
        int m = m0 + chunk * 8 + j;
        if (m < Mdim) {
          int bb = m / 577, tok = m % 577;
          vt[((size_t)(bb * 12 + hh) * 64 + dl) * VSTRIDE + tok] = vv[j];
        }
      }
    }
  }
}

// ---------------- kernel 2: flash attention (softmax-lite) -------------------
// T14: K/V staged via register prefetch + ds_write (no HBM wait in the barrier
// chain). T5: setprio(1) around the QK and PV MFMA clusters.
__global__ __launch_bounds__(256) void attn_kernel(const __bf16* __restrict__ q,
                                                   const __bf16* __restrict__ k,
                                                   const __bf16* __restrict__ vt,
                                                   __bf16* __restrict__ ao) {
  __shared__ __bf16 qs[4096];
  __shared__ __bf16 ks[4096];
  __shared__ __bf16 vs[4096];
  __shared__ __bf16 ps[64 * 72];   // P strip, padded stride 72 (16B-aligned rows)

  // XCD swizzle: all 10 q-tiles of one (b,h) on one XCD -> K/V L2-resident
  const int x8 = blockIdx.x & 7;
  const int rest = blockIdx.x >> 3;
  const int qt = rest % 10;
  const int bh = (rest / 10) * 8 + x8;

  const int t = threadIdx.x;
  const int lane = t & 63, w = t >> 6;
  const int quad = lane >> 4, l16 = lane & 15;

  const __bf16* qbase = q + (size_t)bh * 577 * 64;
  const __bf16* kbase = k + (size_t)bh * 577 * 64;
  const __bf16* vbase = vt + (size_t)bh * 64 * VSTRIDE;

  // stage q tile once: 512 groups of 16B (rows >=577 read poison, discarded)
  #pragma unroll
  for (int p = 0; p < 2; ++p) {
    int g = p * 256 + t;
    int d8 = g >> 6, tok = g & 63;
    gl_lds16(qbase + (size_t)(qt * 64 + tok) * 64 + d8 * 8, qs + (size_t)g * 8);
  }

  // K/V tile 0 -> registers (same (g -> d8,tok) mapping the LDS layout uses)
  bf16x8 kreg[2], vreg[2];
  #pragma unroll
  for (int p = 0; p < 2; ++p) {
    int g = p * 256 + t;
    kreg[p] = *(const bf16x8*)(kbase + (size_t)(g & 63) * 64 + (g >> 6) * 8);
    vreg[p] = *(const bf16x8*)(vbase + (size_t)(g & 63) * VSTRIDE + (g >> 6) * 8);
  }

  f32x4 O[4]; const f32x4 fz = {0.f, 0.f, 0.f, 0.f};
  for (int i = 0; i < 4; ++i) O[i] = fz;
  float l_part[4] = {0.f, 0.f, 0.f, 0.f};

  for (int kt = 0; kt < 10; ++kt) {
    __syncthreads();   // all readers of ks/vs (tile kt-1) done; kt=0: drains q-stage vmcnt
    #pragma unroll
    for (int p = 0; p < 2; ++p) {
      int g = p * 256 + t;
      *(bf16x8*)(ks + (size_t)g * 8) = kreg[p];   // k: [d8][tok][8]
      *(bf16x8*)(vs + (size_t)g * 8) = vreg[p];   // v: [tok8][d][8]
    }
    __syncthreads();   // ds_writes visible to all waves

    // issue next tile's loads NOW; they complete under this tile's compute
    if (kt < 9) {
      #pragma unroll
      for (int p = 0; p < 2; ++p) {
        int g = p * 256 + t;
        kreg[p] = *(const bf16x8*)(kbase + (size_t)((kt + 1) * 64 + (g & 63)) * 64 + (g >> 6) * 8);
        vreg[p] = *(const bf16x8*)(vbase + (size_t)(g & 63) * VSTRIDE + (kt + 1) * 64 + (g >> 6) * 8);
      }
      __builtin_amdgcn_sched_barrier(0);   // pin load issue before compute
    }

    // S = q k^T  (q pre-scaled by 0.125*log2e)
    f32x4 S[4]; for (int i = 0; i < 4; ++i) S[i] = fz;
    __builtin_amdgcn_s_setprio(1);
    #pragma unroll
    for (int step = 0; step < 2; ++step) {
      bf16x8 a = *(const bf16x8*)(qs + (size_t)((step * 4 + quad) * 64 + w * 16 + l16) * 8);
      #pragma unroll
      for (int nt = 0; nt < 4; ++nt) {
        bf16x8 b = *(const bf16x8*)(ks + (size_t)((step * 4 + quad) * 64 + nt * 16 + l16) * 8);
        S[nt] = __builtin_amdgcn_mfma_f32_16x16x32_bf16(a, b, S[nt], 0, 0, 0);
      }
    }
    __builtin_amdgcn_s_setprio(0);

    // mask invalid keys (only kt==9: 577 = 9*64 + 1); exp2(-1e30) -> 0
    int kv_left = 577 - kt * 64;
    if (kv_left < 64) {
      #pragma unroll
      for (int nt = 0; nt < 4; ++nt) {
        int c = nt * 16 + l16;
        if (c >= kv_left) { S[nt][0] = -1e30f; S[nt][1] = -1e30f; S[nt][2] = -1e30f; S[nt][3] = -1e30f; }
      }
    }

    // softmax-lite: exp2, per-lane l accumulation, P -> LDS (A-layout via ps)
    #pragma unroll
    for (int r = 0; r < 4; ++r) {
      #pragma unroll
      for (int nt = 0; nt < 4; ++nt) {
        float e = exp2f(S[nt][r]);
        l_part[r] += e;
        ps[(size_t)(w * 16 + quad * 4 + r) * 72 + nt * 16 + l16] = (__bf16)e;
      }
    }

    // O += P @ V   (P strip is wave-private; in-wave DS ordering covers w->r)
    __builtin_amdgcn_s_setprio(1);
    #pragma unroll
    for (int step = 0; step < 2; ++step) {
      bf16x8 a = *(const bf16x8*)(ps + (size_t)(w * 16 + l16) * 72 + step * 32 + quad * 8);
      #pragma unroll
      for (int dt = 0; dt < 4; ++dt) {
        bf16x8 b = *(const bf16x8*)(vs + (size_t)((step * 4 + quad) * 64 + dt * 16 + l16) * 8);
        O[dt] = __builtin_amdgcn_mfma_f32_16x16x32_bf16(a, b, O[dt], 0, 0, 0);
      }
    }
    __builtin_amdgcn_s_setprio(0);
  }

  // epilogue: reduce l across the 16 col-lanes, normalize, write ao[B*N, C]
  const int bb = bh / 12, hh = bh % 12;
  const int qrow0 = qt * 64 + w * 16 + quad * 4;
  #pragma unroll
  for (int r = 0; r < 4; ++r) {
    float l = l_part[r];
    l += __shfl_xor(l, 1); l += __shfl_xor(l, 2);
    l += __shfl_xor(l, 4); l += __shfl_xor(l, 8);
    int row = qrow0 + r;
    if (row < 577) {
      float inv = 1.f / l;
      size_t base = ((size_t)(bb * 577 + row)) * 768 + hh * 64;
      #pragma unroll
      for (int dt = 0; dt < 4; ++dt)
        ao[base + dt * 16 + l16] = (__bf16)(O[dt][r] * inv);
    }
  }
}

// ---------------- kernel 3: proj GEMM + bias -> fp32 out ---------------------
__global__ __launch_bounds__(256) void proj_kernel(const __bf16* __restrict__ ao,
                                                   const __bf16* __restrict__ wprojT,
                                                   const float* __restrict__ b_proj,
                                                   float* __restrict__ out) {
  __shared__ __bf16 As[2 * 128 * 32];
  __shared__ __bf16 Bs[2 * 128 * 32];
  int nb, mbk;
  if (!xcd_decode(blockIdx.x, 6, 145, nb, mbk)) return;
  const int n0 = nb * 128, m0 = mbk * 128;

  f32x4 acc[4][4];
  const f32x4 fz = {0.f, 0.f, 0.f, 0.f};
  for (int i = 0; i < 4; ++i) for (int j = 0; j < 4; ++j) acc[i][j] = fz;
  gemm_bt_core(ao, wprojT, m0, n0, As, Bs, acc);

  const int lane = threadIdx.x & 63, w = threadIdx.x >> 6;
  const int quad = lane >> 4, l16 = lane & 15;
  const int wm = w >> 1, wn = w & 1;
  const int colbase = n0 + wn * 64;

  #pragma unroll
  for (int mt = 0; mt < 4; ++mt) {
    int mbase = m0 + wm * 64 + mt * 16 + quad * 4;
    #pragma unroll
    for (int r = 0; r < 4; ++r) {
      int m = mbase + r;
      if (m >= Mdim) continue;
      #pragma unroll
      for (int nt = 0; nt < 4; ++nt) {
        int c = colbase + nt * 16 + l16;
        out[(size_t)m * 768 + c] = acc[mt][nt][r] + b_proj[c];
      }
    }
  }
}

// ---------------- launch -----------------------------------------------------
extern "C" void kernel_launch(void* const* d_in, const int* in_sizes, int n_in,
                              void* d_out, int out_size, void* d_ws, size_t ws_size,
                              hipStream_t stream) {
  const float* x      = (const float*)d_in[0];
  const float* w_qkv  = (const float*)d_in[1];
  const float* b_qkv  = (const float*)d_in[2];
  const float* w_proj = (const float*)d_in[3];
  const float* b_proj = (const float*)d_in[4];
  const float* rsn    = (const float*)d_in[5];
  const float* rcs    = (const float*)d_in[6];
  float* out = (float*)d_out;

  // workspace layout (bf16 elements); ao aliases x_bf (x consumed before attn)
  constexpr size_t QK_E = (size_t)Bdim * Hdim * Ndim * Ddim;      // 14,180,352
  constexpr size_t VT_E = (size_t)Bdim * Hdim * Ddim * VSTRIDE;   // 15,728,640
  constexpr size_t AO_E = (size_t)Mdim * Cdim;                    // 14,180,352
  __bf16* q      = (__bf16*)d_ws;
  __bf16* k      = q + QK_E;
  __bf16* vt     = k + QK_E;
  __bf16* ao     = vt + VT_E;        // also holds x_bf before attn runs
  __bf16* xb     = ao;
  __bf16* wqkvF  = ao + AO_E;        // fragment-major qkv weights
  __bf16* wprojT = wqkvF + (size_t)2304 * 768;
  // total: ~121 MB

  f32_to_bf16<<<13848, 256, 0, stream>>>((const float4*)x, (bf16x4*)xb,
                                         (int)(AO_E / 4));
  transpose_f32_wfrag<<<dim3(36, 12), 256, 0, stream>>>(w_qkv, wqkvF);
  transpose_f32_bf16<<<dim3(12, 12), 256, 0, stream>>>(w_proj, wprojT, 768, 768);
  qk_kernel<<<8 * MGRP * 12, 256, 0, stream>>>(xb, wqkvF, b_qkv, rsn, rcs, q, k);
  v_kernel<<<8 * MGRP * 6, 256, 0, stream>>>(xb, wqkvF, b_qkv, vt);
  attn_kernel<<<3840, 256, 0, stream>>>(q, k, vt, ao);
  proj_kernel<<<8 * MGRP * 6, 256, 0, stream>>>(ao, wprojT, b_proj, out);
}